// Round 1
// baseline (1041.029 us; speedup 1.0000x reference)
//
#include <hip/hip_runtime.h>
#include <math.h>

// ---------------------------------------------------------------------------
// ContrastiveEnergyLearning: fused bf16-MFMA MLP energy + contrastive loss
// Inputs (f32): anchor(32768,256) positive(32768,256) negatives(32768,16,256)
//   W1(256,512) b1(256) W2(128,256) b2(128) W3(64,128) b3(64) W4(1,64) b4(1)
// Output (f32 x4): loss, pos_energy, neg_energy, accuracy
// ---------------------------------------------------------------------------

#define NROWS 32768
#define NC 17
#define NPAIRS (NROWS * NC)   // 557056 = 64 * 8704
#define INV_T (1.0f / 0.07f)

using bf16x8 = __attribute__((ext_vector_type(8))) short;
using f32x4  = __attribute__((ext_vector_type(4))) float;

// packed weight layout (bf16 element offsets in ws)
#define PK_W1A 0         // 128 tiles * 512
#define PK_W1Y 65536     // 128 tiles * 512
#define PK_W2  131072    // 64 tiles * 512
#define PK_W3  163840    // 16 tiles * 512
#define APRE_OFF_BYTES 344064
#define EN_OFF_BYTES   (344064 + (size_t)NROWS * 256 * 4)

__device__ inline unsigned short f2b(float f) {
  union { float f; unsigned u; } v; v.f = f;
  return (unsigned short)((v.u + 0x7FFFu + ((v.u >> 16) & 1u)) >> 16);
}
__device__ inline float b2f(unsigned short b) {
  union { unsigned u; float f; } v; v.u = ((unsigned)b) << 16; return v.f;
}
__device__ inline float gelu_f(float x) {
  return 0.5f * x * (1.0f + erff(x * 0.7071067811865476f));
}

__global__ void zero_k(float* out) {
  if (threadIdx.x < 4) out[threadIdx.x] = 0.0f;
}

// Pack W[n][k] -> B-fragment layout: frag[tile][lane][j] = B[k][n] = W[n][koff+k]
// with k = kt*32 + (lane>>4)*8 + j, n = nt*16 + (lane&15), tile = kt*NT + nt.
__global__ void pack_w(const float* __restrict__ W1, const float* __restrict__ W2,
                       const float* __restrict__ W3, unsigned short* __restrict__ pk) {
  int gid = blockIdx.x * 256 + threadIdx.x;   // 336 tiles * 64 lanes = 21504
  int tile = gid >> 6, lane = gid & 63;
  const float* W; int NT, ld, koff, lt; unsigned short* dst;
  if (tile < 128)      { W = W1; NT = 16; ld = 512; koff = 0;   lt = tile;       dst = pk + PK_W1A; }
  else if (tile < 256) { W = W1; NT = 16; ld = 512; koff = 256; lt = tile - 128; dst = pk + PK_W1Y; }
  else if (tile < 320) { W = W2; NT = 8;  ld = 256; koff = 0;   lt = tile - 256; dst = pk + PK_W2;  }
  else                 { W = W3; NT = 4;  ld = 128; koff = 0;   lt = tile - 320; dst = pk + PK_W3;  }
  int kt = lt / NT, nt = lt - kt * NT;
  int k = kt * 32 + (lane >> 4) * 8;
  int n = nt * 16 + (lane & 15);
  const float* src = W + (size_t)n * ld + koff + k;
  unsigned short o[8];
#pragma unroll
  for (int j = 0; j < 8; ++j) o[j] = f2b(src[j]);
  ushort4* d = (ushort4*)(dst + ((size_t)lt * 64 + lane) * 8);
  d[0] = make_ushort4(o[0], o[1], o[2], o[3]);
  d[1] = make_ushort4(o[4], o[5], o[6], o[7]);
}

// apre[m][n] = anchor[m] @ W1a^T + b1  (f32), M-tile = 64 rows / block
__global__ __launch_bounds__(256) void apre_k(const float* __restrict__ anchor,
                                              const float* __restrict__ b1,
                                              const unsigned short* __restrict__ pk,
                                              float* __restrict__ apre) {
  __shared__ __align__(16) unsigned short bufA[64 * 264];
  int t = threadIdx.x;
  int m0 = blockIdx.x * 64;
  for (int it = 0; it < 16; ++it) {
    int e = (it * 256 + t) * 4;
    int m = e >> 8, k = e & 255;
    float4 v = *(const float4*)(anchor + (size_t)(m0 + m) * 256 + k);
    *(ushort4*)&bufA[m * 264 + k] = make_ushort4(f2b(v.x), f2b(v.y), f2b(v.z), f2b(v.w));
  }
  __syncthreads();
  int wave = t >> 6, lane = t & 63, quad = lane >> 4, lid = lane & 15;
  f32x4 acc[4][4];
#pragma unroll
  for (int i = 0; i < 4; ++i)
#pragma unroll
    for (int j = 0; j < 4; ++j) { acc[i][j][0]=0.f; acc[i][j][1]=0.f; acc[i][j][2]=0.f; acc[i][j][3]=0.f; }
  const bf16x8* Wb = (const bf16x8*)(pk + PK_W1A);
  for (int kt = 0; kt < 8; ++kt) {
    bf16x8 a[4], b[4];
#pragma unroll
    for (int mt = 0; mt < 4; ++mt)
      a[mt] = *(const bf16x8*)&bufA[(mt * 16 + lid) * 264 + kt * 32 + quad * 8];
#pragma unroll
    for (int nt = 0; nt < 4; ++nt)
      b[nt] = Wb[(size_t)(kt * 16 + wave * 4 + nt) * 64 + lane];
#pragma unroll
    for (int mt = 0; mt < 4; ++mt)
#pragma unroll
      for (int nt = 0; nt < 4; ++nt)
        acc[mt][nt] = __builtin_amdgcn_mfma_f32_16x16x32_bf16(a[mt], b[nt], acc[mt][nt], 0, 0, 0);
  }
#pragma unroll
  for (int mt = 0; mt < 4; ++mt)
#pragma unroll
    for (int nt = 0; nt < 4; ++nt) {
      int n = wave * 64 + nt * 16 + lid;
      float bias = b1[n];
#pragma unroll
      for (int r = 0; r < 4; ++r) {
        int m = mt * 16 + quad * 4 + r;
        apre[(size_t)(m0 + m) * 256 + n] = acc[mt][nt][r] + bias;
      }
    }
}

// Fused per-pair MLP: 64 pairs per block.
__global__ __launch_bounds__(256) void fused_k(const float* __restrict__ positive,
                                               const float* __restrict__ negatives,
                                               const float* __restrict__ apre,
                                               const unsigned short* __restrict__ pk,
                                               const float* __restrict__ b2v,
                                               const float* __restrict__ b3v,
                                               const float* __restrict__ W4,
                                               const float* __restrict__ b4v,
                                               float* __restrict__ energies) {
  __shared__ __align__(16) unsigned short bufA[64 * 264];  // y, then h1, then h3
  __shared__ __align__(16) unsigned short bufC[64 * 136];  // h2
  __shared__ float apre_s[5 * 256];
  int t = threadIdx.x;
  int p0 = blockIdx.x * 64;
  int r0 = p0 / 17;
  int rN = (p0 + 63) / 17 - r0 + 1;   // <= 5
  for (int i = t; i < rN * 256; i += 256)
    apre_s[i] = apre[(size_t)(r0 + (i >> 8)) * 256 + (i & 255)];
  for (int it = 0; it < 16; ++it) {
    int e = (it * 256 + t) * 4;
    int m = e >> 8, k = e & 255;
    int p = p0 + m;
    int r = p / 17, c = p - r * 17;
    const float* src = (c == 0) ? (positive + (size_t)r * 256)
                                : (negatives + ((size_t)r * 16 + (c - 1)) * 256);
    float4 v = *(const float4*)(src + k);
    *(ushort4*)&bufA[m * 264 + k] = make_ushort4(f2b(v.x), f2b(v.y), f2b(v.z), f2b(v.w));
  }
  __syncthreads();
  int wave = t >> 6, lane = t & 63, quad = lane >> 4, lid = lane & 15;

  // ---- GEMM1: pre1 = y @ W1y^T ; h1 = gelu(pre1 + apre)
  f32x4 acc[4][4];
#pragma unroll
  for (int i = 0; i < 4; ++i)
#pragma unroll
    for (int j = 0; j < 4; ++j) { acc[i][j][0]=0.f; acc[i][j][1]=0.f; acc[i][j][2]=0.f; acc[i][j][3]=0.f; }
  {
    const bf16x8* Wb = (const bf16x8*)(pk + PK_W1Y);
    for (int kt = 0; kt < 8; ++kt) {
      bf16x8 a[4], b[4];
#pragma unroll
      for (int mt = 0; mt < 4; ++mt)
        a[mt] = *(const bf16x8*)&bufA[(mt * 16 + lid) * 264 + kt * 32 + quad * 8];
#pragma unroll
      for (int nt = 0; nt < 4; ++nt)
        b[nt] = Wb[(size_t)(kt * 16 + wave * 4 + nt) * 64 + lane];
#pragma unroll
      for (int mt = 0; mt < 4; ++mt)
#pragma unroll
        for (int nt = 0; nt < 4; ++nt)
          acc[mt][nt] = __builtin_amdgcn_mfma_f32_16x16x32_bf16(a[mt], b[nt], acc[mt][nt], 0, 0, 0);
    }
  }
  __syncthreads();  // all waves done reading y from bufA
#pragma unroll
  for (int mt = 0; mt < 4; ++mt)
#pragma unroll
    for (int nt = 0; nt < 4; ++nt) {
      int n = wave * 64 + nt * 16 + lid;
#pragma unroll
      for (int r = 0; r < 4; ++r) {
        int m = mt * 16 + quad * 4 + r;
        int ri = (p0 + m) / 17 - r0;
        float val = acc[mt][nt][r] + apre_s[ri * 256 + n];
        bufA[m * 264 + n] = f2b(gelu_f(val));
      }
    }
  __syncthreads();

  // ---- GEMM2: h2 = gelu(h1 @ W2^T + b2), N=128 (2 ntiles / wave)
  f32x4 acc2[4][2];
#pragma unroll
  for (int i = 0; i < 4; ++i)
#pragma unroll
    for (int j = 0; j < 2; ++j) { acc2[i][j][0]=0.f; acc2[i][j][1]=0.f; acc2[i][j][2]=0.f; acc2[i][j][3]=0.f; }
  {
    const bf16x8* Wb = (const bf16x8*)(pk + PK_W2);
    for (int kt = 0; kt < 8; ++kt) {
      bf16x8 a[4], b[2];
#pragma unroll
      for (int mt = 0; mt < 4; ++mt)
        a[mt] = *(const bf16x8*)&bufA[(mt * 16 + lid) * 264 + kt * 32 + quad * 8];
#pragma unroll
      for (int nt = 0; nt < 2; ++nt)
        b[nt] = Wb[(size_t)(kt * 8 + wave * 2 + nt) * 64 + lane];
#pragma unroll
      for (int mt = 0; mt < 4; ++mt)
#pragma unroll
        for (int nt = 0; nt < 2; ++nt)
          acc2[mt][nt] = __builtin_amdgcn_mfma_f32_16x16x32_bf16(a[mt], b[nt], acc2[mt][nt], 0, 0, 0);
    }
  }
#pragma unroll
  for (int mt = 0; mt < 4; ++mt)
#pragma unroll
    for (int nt = 0; nt < 2; ++nt) {
      int n = wave * 32 + nt * 16 + lid;
      float bias = b2v[n];
#pragma unroll
      for (int r = 0; r < 4; ++r) {
        int m = mt * 16 + quad * 4 + r;
        bufC[m * 136 + n] = f2b(gelu_f(acc2[mt][nt][r] + bias));
      }
    }
  __syncthreads();

  // ---- GEMM3: h3 = gelu(h2 @ W3^T + b3), N=64 (1 ntile / wave)
  f32x4 acc3[4];
#pragma unroll
  for (int i = 0; i < 4; ++i) { acc3[i][0]=0.f; acc3[i][1]=0.f; acc3[i][2]=0.f; acc3[i][3]=0.f; }
  {
    const bf16x8* Wb = (const bf16x8*)(pk + PK_W3);
    for (int kt = 0; kt < 4; ++kt) {
      bf16x8 a[4];
#pragma unroll
      for (int mt = 0; mt < 4; ++mt)
        a[mt] = *(const bf16x8*)&bufC[(mt * 16 + lid) * 136 + kt * 32 + quad * 8];
      bf16x8 b = Wb[(size_t)(kt * 4 + wave) * 64 + lane];
#pragma unroll
      for (int mt = 0; mt < 4; ++mt)
        acc3[mt] = __builtin_amdgcn_mfma_f32_16x16x32_bf16(a[mt], b, acc3[mt], 0, 0, 0);
    }
  }
  {
    int n = wave * 16 + lid;
    float bias = b3v[n];
#pragma unroll
    for (int mt = 0; mt < 4; ++mt)
#pragma unroll
      for (int r = 0; r < 4; ++r) {
        int m = mt * 16 + quad * 4 + r;
        bufA[m * 72 + n] = f2b(gelu_f(acc3[mt][r] + bias));  // bufA free (h1 fully consumed)
      }
  }
  __syncthreads();

  // ---- layer 4: energy = h3 . w4 + b4
  if (t < 64) {
    float s = b4v[0];
#pragma unroll
    for (int kk = 0; kk < 64; ++kk) s += b2f(bufA[t * 72 + kk]) * W4[kk];
    energies[p0 + t] = s;
  }
}

__global__ __launch_bounds__(256) void reduce_k(const float* __restrict__ E,
                                                float* __restrict__ out) {
  __shared__ float sd[256];
  int r = blockIdx.x * 256 + threadIdx.x;  // grid 128*256 == 32768 rows exactly
  const float* ep = E + (size_t)r * 17;
  float e[17];
#pragma unroll
  for (int i = 0; i < 17; ++i) e[i] = ep[i];
  float li[17];
#pragma unroll
  for (int i = 0; i < 17; ++i) li[i] = -e[i] * INV_T;
  float lmax = li[0];
#pragma unroll
  for (int i = 1; i < 17; ++i) lmax = fmaxf(lmax, li[i]);
  float se = 0.f;
#pragma unroll
  for (int i = 0; i < 17; ++i) se += expf(li[i] - lmax);
  float loss_t = (logf(se) + lmax) - li[0];
  float posv = e[0];
  float negv = 0.f;
#pragma unroll
  for (int i = 1; i < 17; ++i) negv += e[i];
  int mi = 0; float mv = e[0];
#pragma unroll
  for (int i = 1; i < 17; ++i) if (e[i] < mv) { mv = e[i]; mi = i; }
  float accv = (mi == 0) ? 1.f : 0.f;

  float vals[4] = { loss_t, posv, negv, accv };
  const float scales[4] = { 1.0f / NROWS, 1.0f / NROWS, 1.0f / (NROWS * 16.0f), 1.0f / NROWS };
#pragma unroll
  for (int j = 0; j < 4; ++j) {
    sd[threadIdx.x] = vals[j];
    __syncthreads();
    for (int s = 128; s > 0; s >>= 1) {
      if (threadIdx.x < s) sd[threadIdx.x] += sd[threadIdx.x + s];
      __syncthreads();
    }
    if (threadIdx.x == 0) atomicAdd(out + j, sd[0] * scales[j]);
    __syncthreads();
  }
}

extern "C" void kernel_launch(void* const* d_in, const int* in_sizes, int n_in,
                              void* d_out, int out_size, void* d_ws, size_t ws_size,
                              hipStream_t stream) {
  (void)in_sizes; (void)n_in; (void)out_size; (void)ws_size;
  const float* anchor    = (const float*)d_in[0];
  const float* positive  = (const float*)d_in[1];
  const float* negatives = (const float*)d_in[2];
  const float* W1 = (const float*)d_in[3];
  const float* b1 = (const float*)d_in[4];
  const float* W2 = (const float*)d_in[5];
  const float* b2 = (const float*)d_in[6];
  const float* W3 = (const float*)d_in[7];
  const float* b3 = (const float*)d_in[8];
  const float* W4 = (const float*)d_in[9];
  const float* b4 = (const float*)d_in[10];
  float* out = (float*)d_out;
  unsigned short* pk = (unsigned short*)d_ws;
  float* apre = (float*)((char*)d_ws + APRE_OFF_BYTES);
  float* energies = (float*)((char*)d_ws + EN_OFF_BYTES);

  hipLaunchKernelGGL(zero_k, dim3(1), dim3(64), 0, stream, out);
  hipLaunchKernelGGL(pack_w, dim3(84), dim3(256), 0, stream, W1, W2, W3, pk);
  hipLaunchKernelGGL(apre_k, dim3(512), dim3(256), 0, stream, anchor, b1, pk, apre);
  hipLaunchKernelGGL(fused_k, dim3(8704), dim3(256), 0, stream,
                     positive, negatives, apre, pk, b2, b3, W4, b4, energies);
  hipLaunchKernelGGL(reduce_k, dim3(128), dim3(256), 0, stream, energies, out);
}

// Round 2
// 866.036 us; speedup vs baseline: 1.2021x; 1.2021x over previous
//
#include <hip/hip_runtime.h>
#include <math.h>

// ---------------------------------------------------------------------------
// ContrastiveEnergyLearning: fused bf16-MFMA MLP energy + contrastive loss
// R2: fast tanh-GELU (8 VALU ops vs ~25 for erff), LDS union (50 KB -> 3
// blocks/CU), packed bf16 cvt, hoisted /17 divides.
// ---------------------------------------------------------------------------

#define NROWS 32768
#define NC 17
#define NPAIRS (NROWS * NC)   // 557056 = 64 * 8704
#define INV_T (1.0f / 0.07f)

using bf16x8 = __attribute__((ext_vector_type(8))) short;
using f32x4  = __attribute__((ext_vector_type(4))) float;

// packed weight layout (bf16 element offsets in ws)
#define PK_W1A 0         // 128 tiles * 512
#define PK_W1Y 65536     // 128 tiles * 512
#define PK_W2  131072    // 64 tiles * 512
#define PK_W3  163840    // 16 tiles * 512
#define APRE_OFF_BYTES 344064
#define EN_OFF_BYTES   (344064 + (size_t)NROWS * 256 * 4)

__device__ inline unsigned short f2b(float f) {
  union { float f; unsigned u; } v; v.f = f;
  return (unsigned short)((v.u + 0x7FFFu + ((v.u >> 16) & 1u)) >> 16);
}
__device__ inline unsigned f2b2(float a, float b) {   // pack two bf16 (RNE) into u32
#if __has_builtin(__builtin_amdgcn_cvt_pk_bf16_f32)
  typedef __attribute__((ext_vector_type(2))) short s2;
  union { s2 s; unsigned u; } v; v.s = __builtin_amdgcn_cvt_pk_bf16_f32(a, b);
  return v.u;
#else
  return (unsigned)f2b(a) | ((unsigned)f2b(b) << 16);
#endif
}
__device__ inline float b2f(unsigned short b) {
  union { unsigned u; float f; } v; v.u = ((unsigned)b) << 16; return v.f;
}
// tanh-form GELU: x * sigmoid(1.5957691x + 0.0713584x^3). ~8 VALU ops.
// max |delta| vs exact-erf gelu ~3e-3 — well inside the 5.7e-2 threshold.
__device__ inline float gelu_f(float x) {
  float x2 = x * x;
  float w  = x * fmaf(x2, 0.07135837f, 1.59576912f);
  float t  = w * -1.44269504f;
#if __has_builtin(__builtin_amdgcn_exp2f)
  float e  = __builtin_amdgcn_exp2f(t);
#else
  float e  = exp2f(t);
#endif
  return x * __builtin_amdgcn_rcpf(1.0f + e);
}

__global__ void zero_k(float* out) {
  if (threadIdx.x < 4) out[threadIdx.x] = 0.0f;
}

// Pack W[n][k] -> B-fragment layout: frag[tile][lane][j] = W[n][koff+k]
// with k = kt*32 + (lane>>4)*8 + j, n = nt*16 + (lane&15), tile = kt*NT + nt.
__global__ void pack_w(const float* __restrict__ W1, const float* __restrict__ W2,
                       const float* __restrict__ W3, unsigned short* __restrict__ pk) {
  int gid = blockIdx.x * 256 + threadIdx.x;   // 336 tiles * 64 lanes = 21504
  int tile = gid >> 6, lane = gid & 63;
  const float* W; int NT, ld, koff, lt; unsigned short* dst;
  if (tile < 128)      { W = W1; NT = 16; ld = 512; koff = 0;   lt = tile;       dst = pk + PK_W1A; }
  else if (tile < 256) { W = W1; NT = 16; ld = 512; koff = 256; lt = tile - 128; dst = pk + PK_W1Y; }
  else if (tile < 320) { W = W2; NT = 8;  ld = 256; koff = 0;   lt = tile - 256; dst = pk + PK_W2;  }
  else                 { W = W3; NT = 4;  ld = 128; koff = 0;   lt = tile - 320; dst = pk + PK_W3;  }
  int kt = lt / NT, nt = lt - kt * NT;
  int k = kt * 32 + (lane >> 4) * 8;
  int n = nt * 16 + (lane & 15);
  const float* src = W + (size_t)n * ld + koff + k;
  unsigned short o[8];
#pragma unroll
  for (int j = 0; j < 8; ++j) o[j] = f2b(src[j]);
  ushort4* d = (ushort4*)(dst + ((size_t)lt * 64 + lane) * 8);
  d[0] = make_ushort4(o[0], o[1], o[2], o[3]);
  d[1] = make_ushort4(o[4], o[5], o[6], o[7]);
}

// apre[m][n] = anchor[m] @ W1a^T + b1  (f32), M-tile = 64 rows / block
__global__ __launch_bounds__(256) void apre_k(const float* __restrict__ anchor,
                                              const float* __restrict__ b1,
                                              const unsigned short* __restrict__ pk,
                                              float* __restrict__ apre) {
  __shared__ __align__(16) unsigned short bufA[64 * 264];
  int t = threadIdx.x;
  int m0 = blockIdx.x * 64;
  for (int it = 0; it < 16; ++it) {
    int e = (it * 256 + t) * 4;
    int m = e >> 8, k = e & 255;
    float4 v = *(const float4*)(anchor + (size_t)(m0 + m) * 256 + k);
    *(uint2*)&bufA[m * 264 + k] = make_uint2(f2b2(v.x, v.y), f2b2(v.z, v.w));
  }
  __syncthreads();
  int wave = t >> 6, lane = t & 63, quad = lane >> 4, lid = lane & 15;
  f32x4 acc[4][4];
#pragma unroll
  for (int i = 0; i < 4; ++i)
#pragma unroll
    for (int j = 0; j < 4; ++j) { acc[i][j][0]=0.f; acc[i][j][1]=0.f; acc[i][j][2]=0.f; acc[i][j][3]=0.f; }
  const bf16x8* Wb = (const bf16x8*)(pk + PK_W1A);
  for (int kt = 0; kt < 8; ++kt) {
    bf16x8 a[4], b[4];
#pragma unroll
    for (int mt = 0; mt < 4; ++mt)
      a[mt] = *(const bf16x8*)&bufA[(mt * 16 + lid) * 264 + kt * 32 + quad * 8];
#pragma unroll
    for (int nt = 0; nt < 4; ++nt)
      b[nt] = Wb[(size_t)(kt * 16 + wave * 4 + nt) * 64 + lane];
#pragma unroll
    for (int mt = 0; mt < 4; ++mt)
#pragma unroll
      for (int nt = 0; nt < 4; ++nt)
        acc[mt][nt] = __builtin_amdgcn_mfma_f32_16x16x32_bf16(a[mt], b[nt], acc[mt][nt], 0, 0, 0);
  }
#pragma unroll
  for (int mt = 0; mt < 4; ++mt)
#pragma unroll
    for (int nt = 0; nt < 4; ++nt) {
      int n = wave * 64 + nt * 16 + lid;
      float bias = b1[n];
#pragma unroll
      for (int r = 0; r < 4; ++r) {
        int m = mt * 16 + quad * 4 + r;
        apre[(size_t)(m0 + m) * 256 + n] = acc[mt][nt][r] + bias;
      }
    }
}

// Fused per-pair MLP: 64 pairs per block.
__global__ __launch_bounds__(256) void fused_k(const float* __restrict__ positive,
                                               const float* __restrict__ negatives,
                                               const float* __restrict__ apre,
                                               const unsigned short* __restrict__ pk,
                                               const float* __restrict__ b2v,
                                               const float* __restrict__ b3v,
                                               const float* __restrict__ W4,
                                               const float* __restrict__ b4v,
                                               float* __restrict__ energies) {
  __shared__ __align__(16) unsigned short bufA[64 * 264];  // y, then h1, then h3 (33792 B)
  __shared__ __align__(16) unsigned char bufCmem[64 * 136 * 2]; // h2 (17408 B); apre_s overlays
  unsigned short* bufC = (unsigned short*)bufCmem;
  float* apre_s = (float*)bufCmem;   // 5*256*4 = 5120 B, dead before first bufC write
  int t = threadIdx.x;
  int p0 = blockIdx.x * 64;
  int r0 = p0 / 17;
  int rN = (p0 + 63) / 17 - r0 + 1;   // <= 5
  for (int i = t; i < rN * 256; i += 256)
    apre_s[i] = apre[(size_t)(r0 + (i >> 8)) * 256 + (i & 255)];
  for (int it = 0; it < 16; ++it) {
    int e = (it * 256 + t) * 4;
    int m = e >> 8, k = e & 255;
    int p = p0 + m;
    int r = p / 17, c = p - r * 17;
    const float* src = (c == 0) ? (positive + (size_t)r * 256)
                                : (negatives + ((size_t)r * 16 + (c - 1)) * 256);
    float4 v = *(const float4*)(src + k);
    *(uint2*)&bufA[m * 264 + k] = make_uint2(f2b2(v.x, v.y), f2b2(v.z, v.w));
  }
  __syncthreads();
  int wave = t >> 6, lane = t & 63, quad = lane >> 4, lid = lane & 15;

  // ---- GEMM1: pre1 = y @ W1y^T ; h1 = gelu(pre1 + apre)
  f32x4 acc[4][4];
#pragma unroll
  for (int i = 0; i < 4; ++i)
#pragma unroll
    for (int j = 0; j < 4; ++j) { acc[i][j][0]=0.f; acc[i][j][1]=0.f; acc[i][j][2]=0.f; acc[i][j][3]=0.f; }
  {
    const bf16x8* Wb = (const bf16x8*)(pk + PK_W1Y);
    for (int kt = 0; kt < 8; ++kt) {
      bf16x8 a[4], b[4];
#pragma unroll
      for (int mt = 0; mt < 4; ++mt)
        a[mt] = *(const bf16x8*)&bufA[(mt * 16 + lid) * 264 + kt * 32 + quad * 8];
#pragma unroll
      for (int nt = 0; nt < 4; ++nt)
        b[nt] = Wb[(size_t)(kt * 16 + wave * 4 + nt) * 64 + lane];
#pragma unroll
      for (int mt = 0; mt < 4; ++mt)
#pragma unroll
        for (int nt = 0; nt < 4; ++nt)
          acc[mt][nt] = __builtin_amdgcn_mfma_f32_16x16x32_bf16(a[mt], b[nt], acc[mt][nt], 0, 0, 0);
    }
  }
  __syncthreads();  // all waves done reading y from bufA (and apre_s reads below precede bufC writes)
#pragma unroll
  for (int mt = 0; mt < 4; ++mt) {
    int ri[4];
#pragma unroll
    for (int r = 0; r < 4; ++r)
      ri[r] = (p0 + mt * 16 + quad * 4 + r) / 17 - r0;   // hoisted: 16 divides, not 64
#pragma unroll
    for (int nt = 0; nt < 4; ++nt) {
      int n = wave * 64 + nt * 16 + lid;
#pragma unroll
      for (int r = 0; r < 4; ++r) {
        int m = mt * 16 + quad * 4 + r;
        float val = acc[mt][nt][r] + apre_s[ri[r] * 256 + n];
        bufA[m * 264 + n] = f2b(gelu_f(val));
      }
    }
  }
  __syncthreads();

  // ---- GEMM2: h2 = gelu(h1 @ W2^T + b2), N=128 (2 ntiles / wave)
  f32x4 acc2[4][2];
#pragma unroll
  for (int i = 0; i < 4; ++i)
#pragma unroll
    for (int j = 0; j < 2; ++j) { acc2[i][j][0]=0.f; acc2[i][j][1]=0.f; acc2[i][j][2]=0.f; acc2[i][j][3]=0.f; }
  {
    const bf16x8* Wb = (const bf16x8*)(pk + PK_W2);
    for (int kt = 0; kt < 8; ++kt) {
      bf16x8 a[4], b[2];
#pragma unroll
      for (int mt = 0; mt < 4; ++mt)
        a[mt] = *(const bf16x8*)&bufA[(mt * 16 + lid) * 264 + kt * 32 + quad * 8];
#pragma unroll
      for (int nt = 0; nt < 2; ++nt)
        b[nt] = Wb[(size_t)(kt * 8 + wave * 2 + nt) * 64 + lane];
#pragma unroll
      for (int mt = 0; mt < 4; ++mt)
#pragma unroll
        for (int nt = 0; nt < 2; ++nt)
          acc2[mt][nt] = __builtin_amdgcn_mfma_f32_16x16x32_bf16(a[mt], b[nt], acc2[mt][nt], 0, 0, 0);
    }
  }
#pragma unroll
  for (int mt = 0; mt < 4; ++mt)
#pragma unroll
    for (int nt = 0; nt < 2; ++nt) {
      int n = wave * 32 + nt * 16 + lid;
      float bias = b2v[n];
#pragma unroll
      for (int r = 0; r < 4; ++r) {
        int m = mt * 16 + quad * 4 + r;
        bufC[m * 136 + n] = f2b(gelu_f(acc2[mt][nt][r] + bias));
      }
    }
  __syncthreads();

  // ---- GEMM3: h3 = gelu(h2 @ W3^T + b3), N=64 (1 ntile / wave)
  f32x4 acc3[4];
#pragma unroll
  for (int i = 0; i < 4; ++i) { acc3[i][0]=0.f; acc3[i][1]=0.f; acc3[i][2]=0.f; acc3[i][3]=0.f; }
  {
    const bf16x8* Wb = (const bf16x8*)(pk + PK_W3);
    for (int kt = 0; kt < 4; ++kt) {
      bf16x8 a[4];
#pragma unroll
      for (int mt = 0; mt < 4; ++mt)
        a[mt] = *(const bf16x8*)&bufC[(mt * 16 + lid) * 136 + kt * 32 + quad * 8];
      bf16x8 b = Wb[(size_t)(kt * 4 + wave) * 64 + lane];
#pragma unroll
      for (int mt = 0; mt < 4; ++mt)
        acc3[mt] = __builtin_amdgcn_mfma_f32_16x16x32_bf16(a[mt], b, acc3[mt], 0, 0, 0);
    }
  }
  {
    int n = wave * 16 + lid;
    float bias = b3v[n];
#pragma unroll
    for (int mt = 0; mt < 4; ++mt)
#pragma unroll
      for (int r = 0; r < 4; ++r) {
        int m = mt * 16 + quad * 4 + r;
        bufA[m * 72 + n] = f2b(gelu_f(acc3[mt][r] + bias));  // bufA free (h1 fully consumed)
      }
  }
  __syncthreads();

  // ---- layer 4: energy = h3 . w4 + b4
  if (t < 64) {
    float s = b4v[0];
#pragma unroll
    for (int kk = 0; kk < 64; ++kk) s += b2f(bufA[t * 72 + kk]) * W4[kk];
    energies[p0 + t] = s;
  }
}

__global__ __launch_bounds__(256) void reduce_k(const float* __restrict__ E,
                                                float* __restrict__ out) {
  __shared__ float sd[256];
  int r = blockIdx.x * 256 + threadIdx.x;  // grid 128*256 == 32768 rows exactly
  const float* ep = E + (size_t)r * 17;
  float e[17];
#pragma unroll
  for (int i = 0; i < 17; ++i) e[i] = ep[i];
  float li[17];
#pragma unroll
  for (int i = 0; i < 17; ++i) li[i] = -e[i] * INV_T;
  float lmax = li[0];
#pragma unroll
  for (int i = 1; i < 17; ++i) lmax = fmaxf(lmax, li[i]);
  float se = 0.f;
#pragma unroll
  for (int i = 0; i < 17; ++i) se += expf(li[i] - lmax);
  float loss_t = (logf(se) + lmax) - li[0];
  float posv = e[0];
  float negv = 0.f;
#pragma unroll
  for (int i = 1; i < 17; ++i) negv += e[i];
  int mi = 0; float mv = e[0];
#pragma unroll
  for (int i = 1; i < 17; ++i) if (e[i] < mv) { mv = e[i]; mi = i; }
  float accv = (mi == 0) ? 1.f : 0.f;

  float vals[4] = { loss_t, posv, negv, accv };
  const float scales[4] = { 1.0f / NROWS, 1.0f / NROWS, 1.0f / (NROWS * 16.0f), 1.0f / NROWS };
#pragma unroll
  for (int j = 0; j < 4; ++j) {
    sd[threadIdx.x] = vals[j];
    __syncthreads();
    for (int s = 128; s > 0; s >>= 1) {
      if (threadIdx.x < s) sd[threadIdx.x] += sd[threadIdx.x + s];
      __syncthreads();
    }
    if (threadIdx.x == 0) atomicAdd(out + j, sd[0] * scales[j]);
    __syncthreads();
  }
}

extern "C" void kernel_launch(void* const* d_in, const int* in_sizes, int n_in,
                              void* d_out, int out_size, void* d_ws, size_t ws_size,
                              hipStream_t stream) {
  (void)in_sizes; (void)n_in; (void)out_size; (void)ws_size;
  const float* anchor    = (const float*)d_in[0];
  const float* positive  = (const float*)d_in[1];
  const float* negatives = (const float*)d_in[2];
  const float* W1 = (const float*)d_in[3];
  const float* b1 = (const float*)d_in[4];
  const float* W2 = (const float*)d_in[5];
  const float* b2 = (const float*)d_in[6];
  const float* W3 = (const float*)d_in[7];
  const float* b3 = (const float*)d_in[8];
  const float* W4 = (const float*)d_in[9];
  const float* b4 = (const float*)d_in[10];
  float* out = (float*)d_out;
  unsigned short* pk = (unsigned short*)d_ws;
  float* apre = (float*)((char*)d_ws + APRE_OFF_BYTES);
  float* energies = (float*)((char*)d_ws + EN_OFF_BYTES);

  hipLaunchKernelGGL(zero_k, dim3(1), dim3(64), 0, stream, out);
  hipLaunchKernelGGL(pack_w, dim3(84), dim3(256), 0, stream, W1, W2, W3, pk);
  hipLaunchKernelGGL(apre_k, dim3(512), dim3(256), 0, stream, anchor, b1, pk, apre);
  hipLaunchKernelGGL(fused_k, dim3(8704), dim3(256), 0, stream,
                     positive, negatives, apre, pk, b2, b3, W4, b4, energies);
  hipLaunchKernelGGL(reduce_k, dim3(128), dim3(256), 0, stream, energies, out);
}